// Round 11
// baseline (362.646 us; speedup 1.0000x reference)
//
#include <hip/hip_runtime.h>

#define PH  72
#define HSZ 1152
#define XRW 144          // x frag-tile row stride (halves)
#define XSL 584          // per-t-slot stride (4*XRW + 8 pad) halves

typedef float f32x4 __attribute__((ext_vector_type(4)));
typedef _Float16 f16x8 __attribute__((ext_vector_type(8)));

__device__ __forceinline__ float sigmoid_f(float x) {
    float e = __builtin_amdgcn_exp2f(-1.4426950408889634f * x);
    return __builtin_amdgcn_rcpf(1.0f + e);
}
__device__ __forceinline__ float tanh_f(float x) {
    float e = __builtin_amdgcn_exp2f(-2.8853900817779268f * x);
    return 2.0f * __builtin_amdgcn_rcpf(1.0f + e) - 1.0f;
}
__device__ __forceinline__ f16x8 load_frag16h(const float* wp, int n, int K, int k0) {
    const float* wf = wp + (size_t)n * K + k0;
    f16x8 h;
    #pragma unroll
    for (int j = 0; j < 8; ++j) h[j] = (_Float16)wf[j];
    return h;
}
__device__ __forceinline__ void gload16(const void* g, void* l) {
    __builtin_amdgcn_global_load_lds(
        (const __attribute__((address_space(1))) unsigned int*)g,
        (__attribute__((address_space(3))) unsigned int*)l, 16, 0, 0);
}

#define MFMA16(a, b, c) __builtin_amdgcn_mfma_f32_16x16x32_f16(a, b, c, 0, 0, 0)

// ======= fused rec v13: 2-wave merge (L0+proj in one wave) + v11 math =======
// 256 blocks x 512 thr (8 waves: 4 L1, 4 L0; 2 per SIMD).
// v12 post-mortem: batched proj -> ~24 dw/thread scratch AGAIN (WRITE 19MB).
// Updated model: step time == MFMA(676) + VALU(652) + LDS(~850) cy, fully
// serialized (phase-locked waves). v13 reduces the SUM with zero new state:
// proj's x-MFMAs have no barrier dependency (xh written >=5 steps earlier),
// so they fold into L0 as pure ILP:
//   L0: accA = gb + 4 x-ks MFMA (wih0, K=128); accB = 2 h-ks MFMA (whh0);
//       gate = accA[0] + accB[0] + accB[1]  (hi/lo-h M-row packing kept).
//   L1: unchanged v11 (wih1 + whh1 single-plane, 4-deep; hi/lo h rows).
// Deleted: xpl ring (16 KB LDS + its traffic), 4 proj waves (loop/addr/skew).
// MFMA/SIMD/step stays 40. Staging: v6's proven windows (L0 waves own it):
// issue@tn%16==0, convert@tn%16 in 8..11. No cross-barrier register state.
__global__ __launch_bounds__(512, 2) void rec_fused(
    const float* __restrict__ x,
    const float* __restrict__ wih0, const float* __restrict__ whh0,
    const float* __restrict__ bih0, const float* __restrict__ bhh0,
    const float* __restrict__ wih1, const float* __restrict__ whh1,
    const float* __restrict__ bih1, const float* __restrict__ bhh1,
    const float* __restrict__ wfc,  const float* __restrict__ bfc,
    float* __restrict__ out)
{
    __shared__ float    xs32[4 * 2048];          // 32 KB staging strip
    __shared__ _Float16 xh[32 * XSL];            // 37,376 B x frags (f16)
    __shared__ _Float16 h0[2 * HSZ], h1[2 * HSZ];
    const int tid = threadIdx.x, lane = tid & 63, w = tid >> 6;
    const int l16 = lane & 15, quad = lane >> 4, k0 = quad * 8;
    const int wl = w & 3;
    const bool is1 = (w < 4);
    const int bb  = blockIdx.x & 63;
    const int sub = blockIdx.x >> 6;

    const float* xrow = x + (size_t)(bb * 16 + wl * 4 + sub) * 128 * 256;

    f16x8 fA[4][2], fB[4][4];
    float gb[4];
    #pragma unroll
    for (int g = 0; g < 4; ++g) {
        const int n = g * 64 + wl * 16 + l16;
        if (is1) {
            #pragma unroll
            for (int ks = 0; ks < 2; ++ks) {
                fA[g][ks] = load_frag16h(wih1, n, 64, ks * 32 + k0);
                fB[g][ks] = load_frag16h(whh1, n, 64, ks * 32 + k0);
            }
            gb[g] = bih1[n] + bhh1[n];
        } else {
            #pragma unroll
            for (int ks = 0; ks < 4; ++ks)
                fB[g][ks] = load_frag16h(wih0, n, 128, ks * 32 + k0);
            #pragma unroll
            for (int ks = 0; ks < 2; ++ks)
                fA[g][ks] = load_frag16h(whh0, n, 64, ks * 32 + k0);
            gb[g] = bih0[n] + bhh0[n];
        }
    }
    for (int i = tid; i < 2 * HSZ; i += 512) { h0[i] = (_Float16)0.f; h1[i] = (_Float16)0.f; }
    float c = 0.f;       // lane's cell state (c1 for L1, c0 for L0)

    // ---- staging helpers (L0 waves; byte-identical to v6/v11) ----
    auto convert_rows = [&](int cc, int ib0, int nib) {
        const int sb = (cc & 1) * 16;
        const int tq = lane & 3;
        for (int ib = ib0; ib < ib0 + nib; ++ib) {
            const float4 v = *(const float4*)&xs32[wl * 2048 + ib * 256 + lane * 4];
            const int d = ib * 16 + (lane >> 2);
            const float vv[4] = {v.x, v.y, v.z, v.w};
            #pragma unroll
            for (int j = 0; j < 4; ++j)
                xh[(sb + tq * 4 + j) * XSL + wl * XRW + d] = (_Float16)vv[j];
        }
    };
    auto issue_chunk = [&](int cc) {
        #pragma unroll
        for (int ib = 0; ib < 8; ++ib)
            gload16(xrow + (size_t)(ib * 16 + (lane >> 2)) * 256 + cc * 16 + (lane & 3) * 4,
                    (char*)xs32 + wl * 8192 + ib * 1024);
    };
    // hi/lo h store: row quad*4 = hi, row quad*4+1 = residual
    auto store_h = [&](_Float16* hbuf, int slot, float hv) {
        const _Float16 hh = (_Float16)hv;
        const int base = slot * HSZ + (quad * 4) * PH + wl * 16 + l16;
        hbuf[base]      = hh;
        hbuf[base + PH] = (_Float16)(hv - (float)hh);
    };

    if (!is1) issue_chunk(0);
    __syncthreads();                 // strip0 drained; h zeroed
    if (!is1) { convert_rows(0, 0, 8); issue_chunk(1); }
    __syncthreads();                 // xh chunk0 visible; strip1 drained

    if (!is1) {      // prologue: layer0 t=0 (h=0): gates = x.W + b
        f16x8 ax[4];
        #pragma unroll
        for (int ks = 0; ks < 4; ++ks)
            ax[ks] = *(const f16x8*)&xh[(l16 >> 2) * XRW + ks * 32 + k0];
        f32x4 accA[4];
        #pragma unroll
        for (int g = 0; g < 4; ++g) accA[g] = (f32x4){gb[g], gb[g], gb[g], gb[g]};
        #pragma unroll
        for (int g = 0; g < 4; ++g)
            #pragma unroll
            for (int ks = 0; ks < 4; ++ks)
                accA[g] = MFMA16(ax[ks], fB[g][ks], accA[g]);
        const float gi = sigmoid_f(accA[0][0]);
        const float gg = tanh_f(accA[2][0]);
        const float go = sigmoid_f(accA[3][0]);
        c = gi * gg;
        store_h(h0, 0, go * tanh_f(c));
    }
    __syncthreads();

    for (int t = 0; t < 255; ++t) {
        const int s0 = t & 1, s1 = s0 ^ 1;
        const int tn = t + 1;
        if (is1) {
            f16x8 ah[2], bh[2];
            #pragma unroll
            for (int ks = 0; ks < 2; ++ks) {
                ah[ks] = *(const f16x8*)&h0[s0 * HSZ + l16 * PH + ks * 32 + k0];
                bh[ks] = *(const f16x8*)&h1[s1 * HSZ + l16 * PH + ks * 32 + k0];
            }
            f32x4 acc[4];
            #pragma unroll
            for (int g = 0; g < 4; ++g)
                acc[g] = (f32x4){gb[g], 0.f, 0.f, 0.f};
            #pragma unroll
            for (int g = 0; g < 4; ++g)
                #pragma unroll
                for (int ks = 0; ks < 2; ++ks) {
                    acc[g] = MFMA16(ah[ks], fA[g][ks], acc[g]);
                    acc[g] = MFMA16(bh[ks], fB[g][ks], acc[g]);
                }
            const float gi = sigmoid_f(acc[0][0] + acc[0][1]);
            const float gf = sigmoid_f(acc[1][0] + acc[1][1]);
            const float gg = tanh_f(acc[2][0] + acc[2][1]);
            const float go = sigmoid_f(acc[3][0] + acc[3][1]);
            c = gf * c + gi * gg;
            store_h(h1, s0, go * tanh_f(c));
        } else {
            const int slot = tn & 31;
            f16x8 ax[4], ah[2];
            #pragma unroll
            for (int ks = 0; ks < 4; ++ks)
                ax[ks] = *(const f16x8*)&xh[slot * XSL + (l16 >> 2) * XRW + ks * 32 + k0];
            #pragma unroll
            for (int ks = 0; ks < 2; ++ks)
                ah[ks] = *(const f16x8*)&h0[s0 * HSZ + l16 * PH + ks * 32 + k0];
            f32x4 accA[4], accB[4];
            #pragma unroll
            for (int g = 0; g < 4; ++g) {
                accA[g] = (f32x4){gb[g], 0.f, 0.f, 0.f};
                accB[g] = (f32x4){0.f, 0.f, 0.f, 0.f};
            }
            #pragma unroll
            for (int g = 0; g < 4; ++g) {
                #pragma unroll
                for (int ks = 0; ks < 4; ++ks)
                    accA[g] = MFMA16(ax[ks], fB[g][ks], accA[g]);
                #pragma unroll
                for (int ks = 0; ks < 2; ++ks)
                    accB[g] = MFMA16(ah[ks], fA[g][ks], accB[g]);
            }
            const float gi = sigmoid_f(accA[0][0] + accB[0][0] + accB[0][1]);
            const float gf = sigmoid_f(accA[1][0] + accB[1][0] + accB[1][1]);
            const float gg = tanh_f(accA[2][0] + accB[2][0] + accB[2][1]);
            const float go = sigmoid_f(accA[3][0] + accB[3][0] + accB[3][1]);
            c = gf * c + gi * gg;
            store_h(h0, s1, go * tanh_f(c));
            if ((tn & 15) == 0 && tn < 240)         // issue next chunk (DMA)
                issue_chunk((tn >> 4) + 1);
            const int m16 = tn & 15;
            if (m16 >= 8 && m16 < 12 && tn < 248)   // spread strip->frag convert
                convert_rows((tn >> 4) + 1, (m16 - 8) * 2, 2);
        }
        __syncthreads();
    }

    if (is1) {   // epilogue: layer1[255] (h0 slot1, h1 slot0 -> h1 slot1)
        f16x8 ah[2], bh[2];
        #pragma unroll
        for (int ks = 0; ks < 2; ++ks) {
            ah[ks] = *(const f16x8*)&h0[HSZ + l16 * PH + ks * 32 + k0];
            bh[ks] = *(const f16x8*)&h1[l16 * PH + ks * 32 + k0];
        }
        f32x4 acc[4];
        #pragma unroll
        for (int g = 0; g < 4; ++g)
            acc[g] = (f32x4){gb[g], 0.f, 0.f, 0.f};
        #pragma unroll
        for (int g = 0; g < 4; ++g)
            #pragma unroll
            for (int ks = 0; ks < 2; ++ks) {
                acc[g] = MFMA16(ah[ks], fA[g][ks], acc[g]);
                acc[g] = MFMA16(bh[ks], fB[g][ks], acc[g]);
            }
        const float gi = sigmoid_f(acc[0][0] + acc[0][1]);
        const float gf = sigmoid_f(acc[1][0] + acc[1][1]);
        const float gg = tanh_f(acc[2][0] + acc[2][1]);
        const float go = sigmoid_f(acc[3][0] + acc[3][1]);
        c = gf * c + gi * gg;
        store_h(h1, 1, go * tanh_f(c));
    }
    __syncthreads();

    // head: rows sel*4 (hi) + sel*4+1 (lo) of slot 1; out row = bb*16+sel*4+sub
    const int n   = tid & 127;
    const int sel = tid >> 7;
    float s = 0.f;
    for (int k = 0; k < 64; ++k)
        s += ((float)h1[HSZ + (sel * 4) * PH + k]
            + (float)h1[HSZ + (sel * 4 + 1) * PH + k]) * wfc[n * 64 + k];
    out[(size_t)(bb * 16 + sel * 4 + sub) * 128 + n] = s + bfc[n];
}

extern "C" void kernel_launch(void* const* d_in, const int* in_sizes, int n_in,
                              void* d_out, int out_size, void* d_ws, size_t ws_size,
                              hipStream_t stream) {
    const float* x     = (const float*)d_in[0];
    const float* wih0  = (const float*)d_in[1];
    const float* whh0  = (const float*)d_in[2];
    const float* bih0  = (const float*)d_in[3];
    const float* bhh0  = (const float*)d_in[4];
    const float* wih1  = (const float*)d_in[5];
    const float* whh1  = (const float*)d_in[6];
    const float* bih1  = (const float*)d_in[7];
    const float* bhh1  = (const float*)d_in[8];
    const float* wfc   = (const float*)d_in[9];
    const float* bfc   = (const float*)d_in[10];
    float* out = (float*)d_out;

    rec_fused<<<256, 512, 0, stream>>>(x, wih0, whh0, bih0, bhh0,
                                       wih1, whh1, bih1, bhh1, wfc, bfc, out);
}